// Round 1
// baseline (439.427 us; speedup 1.0000x reference)
//
#include <hip/hip_runtime.h>

// reset_layer: Out = R^T · X · L^T + X per (b,h,w), where X is the 10x10 grid
// of 200x200 tiles of the 2000x2000 image. Fully fused single pass.
// Sizes hard-coded to the bench problem: x (16,2000,2000) fp32, bs=10.

#define NB   16
#define IMG  2000
#define BSZ  10
#define TC   200                 // tile (chunk) size = 2000/10
#define CHW  (IMG * IMG)         // 4,000,000
#define ROWSTEP (TC * IMG)       // iH*200 rows down = 400,000 elements

__global__ __launch_bounds__(256, 2)
void reset_block_mix(const float* __restrict__ x,
                     const float* __restrict__ leftm,
                     const float* __restrict__ rightm,
                     float* __restrict__ out) {
    __shared__ float Ls[BSZ * BSZ];
    __shared__ float Rs[BSZ * BSZ];
    const int t = threadIdx.x;
    if (t < 100)       Ls[t]       = leftm[t];
    else if (t < 200)  Rs[t - 100] = rightm[t - 100];
    __syncthreads();

    const int idx = blockIdx.x * 256 + t;   // 0 .. 639,999 exactly (2500 blocks)
    const int w   = idx % TC;
    const int tm  = idx / TC;
    const int h   = tm % TC;
    const int b   = tm / TC;

    const int base = b * CHW + h * IMG + w;

    // ---- load the per-pixel 10x10 block matrix X (coalesced across lanes) ----
    float X[BSZ][BSZ];
    #pragma unroll
    for (int iH = 0; iH < BSZ; ++iH) {
        const int rbase = base + iH * ROWSTEP;
        #pragma unroll
        for (int iW = 0; iW < BSZ; ++iW)
            X[iH][iW] = x[rbase + iW * TC];
    }

    // ---- Y = X · L^T :  Y[iH][jW] = sum_iW L[jW][iW] * X[iH][iW] ----
    // Loop order reads each L coefficient from LDS exactly once (100 ds_reads).
    float Y[BSZ][BSZ];
    #pragma unroll
    for (int jW = 0; jW < BSZ; ++jW) {
        {
            const float l = Ls[jW * BSZ + 0];
            #pragma unroll
            for (int iH = 0; iH < BSZ; ++iH) Y[iH][jW] = l * X[iH][0];
        }
        #pragma unroll
        for (int iW = 1; iW < BSZ; ++iW) {
            const float l = Ls[jW * BSZ + iW];
            #pragma unroll
            for (int iH = 0; iH < BSZ; ++iH) Y[iH][jW] += l * X[iH][iW];
        }
    }

    // ---- Z = R^T · Y + X, accumulated in place into X ----
    // X[jH][jW] += sum_iH R[iH][jH] * Y[iH][jW]; each R read exactly once.
    #pragma unroll
    for (int jH = 0; jH < BSZ; ++jH) {
        #pragma unroll
        for (int iH = 0; iH < BSZ; ++iH) {
            const float r = Rs[iH * BSZ + jH];
            #pragma unroll
            for (int jW = 0; jW < BSZ; ++jW)
                X[jH][jW] += r * Y[iH][jW];
        }
    }

    // ---- store (coalesced across lanes) ----
    #pragma unroll
    for (int jH = 0; jH < BSZ; ++jH) {
        const int rbase = base + jH * ROWSTEP;
        #pragma unroll
        for (int jW = 0; jW < BSZ; ++jW)
            out[rbase + jW * TC] = X[jH][jW];
    }
}

extern "C" void kernel_launch(void* const* d_in, const int* in_sizes, int n_in,
                              void* d_out, int out_size, void* d_ws, size_t ws_size,
                              hipStream_t stream) {
    const float* x = (const float*)d_in[0];
    const float* L = (const float*)d_in[1];
    const float* R = (const float*)d_in[2];
    float* out = (float*)d_out;
    // 16 * 200 * 200 = 640,000 threads -> 2500 blocks of 256
    reset_block_mix<<<2500, 256, 0, stream>>>(x, L, R, out);
}